// Round 9
// baseline (72.160 us; speedup 1.0000x reference)
//
#include <hip/hip_runtime.h>

// MeanPoolingWithoutPadding: features [B,S,D] f32, lengths [B] i32,
// out [B,D] f32 = sum_{s<len[b]} f[b,s,:] / len[b].  B=64, S=2048, D=512.
//
// R9: work-queue partial kernel. R8's static grid (2048 blocks = whole grid
// resident, no refill pool) leaves a ~1.4x straggler makespan (per-CU bytes
// ~ sum of 8 length-proportional draws). Here work = 8192 units of 16 rows
// (unit u -> b=u&63, k=u>>6, rows [16k,16k+16) clamped to len). Units
// [0,4096) (rows<1024) are statically assigned 2/block (no atomic burst at
// launch); units [4096,8192) (fat samples' tails -- the imbalanced part)
// are grabbed 2-at-a-time from a global integer counter (relaxed, agent
// scope; ~2048 grabs over ~20us, no ordering/fence semantics -- R3's 13x
// was fences, R7's 1.4x was 1M float RMWs; this is neither).
// Determinism: each unit writes its own ws slice regardless of which block
// runs it; counter zeroed per call by a 4B on-stream memset.
//   pool_final: grid (B,4) x 128 thr reduces the nact=ceil(len/16) written
//   slices per b, divides by len, stores.

#define DDIM 512
#define LD4  (DDIM / 4)     // float4 per row
#define TPB  128
#define RPU  16             // rows per unit
#define KMAX 128            // units per b = S/RPU
#define BMAX 64
#define NUNITS  (BMAX * KMAX)   // 8192
#define NSTATIC 4096            // units [0,NSTATIC) static, rest queued
#define NQUEUED (NUNITS - NSTATIC)
#define NBLK    (NSTATIC / 2)   // 2048 blocks, 2 static units each

__device__ __forceinline__ void acc4(float4& a, const float4& v) {
    a.x += v.x; a.y += v.y; a.z += v.z; a.w += v.w;
}

__device__ __forceinline__ void do_unit(unsigned u, const float4* __restrict__ featf4,
                                        const int* __restrict__ lengths,
                                        float4* __restrict__ wsf4, int S, int t) {
    const int b   = (int)(u & 63u);
    const int k   = (int)(u >> 6);
    const int len = lengths[b];
    const int s0  = k * RPU;
    if (s0 >= len) return;                 // empty unit: never read by final
    const int s1  = min(s0 + RPU, len);

    const float4* __restrict__ base = featf4 + (size_t)b * S * LD4 + t;

    float4 a0 = {0.f,0.f,0.f,0.f};
    float4 a1 = {0.f,0.f,0.f,0.f};
    float4 a2 = {0.f,0.f,0.f,0.f};
    float4 a3 = {0.f,0.f,0.f,0.f};
    int s = s0;
    for (; s + 3 < s1; s += 4) {
        float4 v0 = base[(size_t)(s + 0) * LD4];
        float4 v1 = base[(size_t)(s + 1) * LD4];
        float4 v2 = base[(size_t)(s + 2) * LD4];
        float4 v3 = base[(size_t)(s + 3) * LD4];
        acc4(a0, v0); acc4(a1, v1); acc4(a2, v2); acc4(a3, v3);
    }
    for (; s < s1; ++s) acc4(a0, base[(size_t)s * LD4]);
    acc4(a0, a1); acc4(a2, a3); acc4(a0, a2);

    wsf4[(size_t)u * LD4 + t] = a0;
}

__global__ void __launch_bounds__(TPB)
pool_partial_q(const float* __restrict__ feat, const int* __restrict__ lengths,
               float* __restrict__ ws, unsigned* __restrict__ cnt, int S) {
    const int t = threadIdx.x;
    const float4* featf4 = reinterpret_cast<const float4*>(feat);
    float4* wsf4 = reinterpret_cast<float4*>(ws);

    // Static pair: units 2*id, 2*id+1 (covers [0, NSTATIC)).
    const unsigned u0 = blockIdx.x * 2u;
    do_unit(u0,     featf4, lengths, wsf4, S, t);
    do_unit(u0 + 1, featf4, lengths, wsf4, S, t);

    // Dynamic refill from the queued range [NSTATIC, NUNITS).
    __shared__ unsigned sbase;
    for (;;) {
        if (t == 0) {
            sbase = __hip_atomic_fetch_add(cnt, 2u, __ATOMIC_RELAXED,
                                           __HIP_MEMORY_SCOPE_AGENT);
        }
        __syncthreads();
        const unsigned base = sbase;
        __syncthreads();                   // sbase consumed before next write
        if (base >= NQUEUED) break;
        do_unit(NSTATIC + base, featf4, lengths, wsf4, S, t);
        if (base + 1 < NQUEUED)
            do_unit(NSTATIC + base + 1, featf4, lengths, wsf4, S, t);
    }
}

// grid (B, 4), 128 thr. Block (b,q) owns f4-cols [q*32, q*32+32).
__global__ void __launch_bounds__(TPB)
pool_final(const float* __restrict__ ws, const int* __restrict__ lengths,
           float* __restrict__ out) {
    const int b    = blockIdx.x;
    const int q    = blockIdx.y;
    const int t    = threadIdx.x;
    const int lane = t & 31;
    const int rg   = t >> 5;
    const int col  = q * 32 + lane;

    const int len  = lengths[b];
    const int nact = (len + RPU - 1) / RPU;   // exactly the written k's

    const float4* wsf4 = reinterpret_cast<const float4*>(ws);

    float4 a  = {0.f,0.f,0.f,0.f};
    float4 a2 = {0.f,0.f,0.f,0.f};
    int k = rg;
    for (; k + 4 < nact; k += 8) {
        float4 w0 = wsf4[(size_t)(b + 64 * k)       * LD4 + col];
        float4 w1 = wsf4[(size_t)(b + 64 * (k + 4)) * LD4 + col];
        acc4(a, w0); acc4(a2, w1);
    }
    for (; k < nact; k += 4) acc4(a, wsf4[(size_t)(b + 64 * k) * LD4 + col]);
    acc4(a, a2);

    __shared__ float4 red[TPB];
    red[t] = a;
    __syncthreads();
    if (rg == 0) {
        acc4(a, red[t + 32]);
        acc4(a, red[t + 64]);
        acc4(a, red[t + 96]);
        const float inv = 1.0f / (float)len;
        float4 r = {a.x * inv, a.y * inv, a.z * inv, a.w * inv};
        reinterpret_cast<float4*>(out + (size_t)b * DDIM)[col] = r;
    }
}

// Generic fallback: one block per b, full S loop, no ws.
__global__ void __launch_bounds__(TPB)
pool_direct(const float* __restrict__ feat, const int* __restrict__ lengths,
            float* __restrict__ out, int S) {
    const int b   = blockIdx.x;
    const int tid = threadIdx.x;
    const int len = lengths[b];
    float4 a0 = {0.f,0.f,0.f,0.f};
    float4 a1 = {0.f,0.f,0.f,0.f};
    float4 a2 = {0.f,0.f,0.f,0.f};
    float4 a3 = {0.f,0.f,0.f,0.f};
    const float4* __restrict__ base =
        reinterpret_cast<const float4*>(feat + (size_t)b * S * DDIM) + tid;
    int s = 0;
    for (; s + 3 < len; s += 4) {
        float4 v0 = base[(size_t)(s + 0) * LD4];
        float4 v1 = base[(size_t)(s + 1) * LD4];
        float4 v2 = base[(size_t)(s + 2) * LD4];
        float4 v3 = base[(size_t)(s + 3) * LD4];
        acc4(a0, v0); acc4(a1, v1); acc4(a2, v2); acc4(a3, v3);
    }
    for (; s < len; ++s) { float4 v = base[(size_t)s * LD4]; acc4(a0, v); }
    acc4(a0, a1); acc4(a2, a3); acc4(a0, a2);
    const float inv = 1.0f / (float)len;
    float4 r = {a0.x * inv, a0.y * inv, a0.z * inv, a0.w * inv};
    reinterpret_cast<float4*>(out + (size_t)b * DDIM)[tid] = r;
}

extern "C" void kernel_launch(void* const* d_in, const int* in_sizes, int n_in,
                              void* d_out, int out_size, void* d_ws, size_t ws_size,
                              hipStream_t stream) {
    const float* feat    = (const float*)d_in[0];
    const int*   lengths = (const int*)d_in[1];
    float*       out     = (float*)d_out;

    const int B = in_sizes[1];                       // 64
    const int S = in_sizes[0] / (B * DDIM);          // 2048

    const size_t slice_bytes = (size_t)NUNITS * DDIM * sizeof(float); // 16 MB
    const size_t need = slice_bytes + sizeof(unsigned);

    if (B == BMAX && S == KMAX * RPU && out_size == B * DDIM && ws_size >= need) {
        float*    ws  = (float*)d_ws;
        unsigned* cnt = (unsigned*)((char*)d_ws + slice_bytes);
        hipMemsetAsync(cnt, 0, sizeof(unsigned), stream);
        dim3 grid2(B, 4);
        pool_partial_q<<<NBLK, TPB, 0, stream>>>(feat, lengths, ws, cnt, S);
        pool_final<<<grid2, TPB, 0, stream>>>(ws, lengths, out);
    } else {
        pool_direct<<<B, TPB, 0, stream>>>(feat, lengths, out, S);
    }
}

// Round 10
// 37.327 us; speedup vs baseline: 1.9332x; 1.9332x over previous
//
#include <hip/hip_runtime.h>

// MeanPoolingWithoutPadding: features [B,S,D] f32, lengths [B] i32,
// out [B,D] f32 = sum_{s<len[b]} f[b,s,:] / len[b].  B=64, S=2048, D=512.
//
// R10 = R8 (best, 29.4 us) + read-side micro-tuning only:
//   - inner loop: 8 independent accumulators / 8 outstanding 16B loads per
//     wave (R8 had 4; VGPR reuse at the backedge capped MLP)
//   - __builtin_nontemporal_load on the feature stream (134 MB streamed
//     through 32 MB aggregate L2 -> bypass-hint avoids alloc/evict churn)
// Structure unchanged: partial grid (B,DQ=4,NS=8)=2048 blocks x 128 thr,
// ws = 1 MB; final grid (B,4) x 128 thr. No atomics (R7), no fences (R3),
// no dynamic queue (R9) -- all measured regressions.

#define DDIM 512
#define LD4  (DDIM / 4)   // 128 float4 per row
#define NS   8
#define DQ   4
#define TPB  128

typedef float v4 __attribute__((ext_vector_type(4)));

__global__ void __launch_bounds__(TPB)
pool_partial(const float* __restrict__ feat, const int* __restrict__ lengths,
             float* __restrict__ ws, int S) {
    const int b     = blockIdx.x;
    const int q     = blockIdx.y;        // D-slice
    const int split = blockIdx.z;        // S-slice
    const int t     = threadIdx.x;
    const int lane  = t & 31;            // col lane: 32 f4 = 512 B
    const int rg    = t >> 5;            // row group 0..3

    const int len   = lengths[b];
    const int chunk = (len + NS - 1) / NS;
    const int s0 = split * chunk;
    if (s0 >= len) return;               // inactive: final never reads it
    const int s1 = min(s0 + chunk, len);

    const int col = q * 32 + lane;       // f4 column index
    const v4* __restrict__ base =
        reinterpret_cast<const v4*>(feat + (size_t)b * S * DDIM) + col;

    v4 a0 = {0.f,0.f,0.f,0.f};
    v4 a1 = {0.f,0.f,0.f,0.f};
    v4 a2 = {0.f,0.f,0.f,0.f};
    v4 a3 = {0.f,0.f,0.f,0.f};
    v4 a4 = {0.f,0.f,0.f,0.f};
    v4 a5 = {0.f,0.f,0.f,0.f};
    v4 a6 = {0.f,0.f,0.f,0.f};
    v4 a7 = {0.f,0.f,0.f,0.f};

    int s = s0 + rg;                     // this rg covers rows s0+rg, +4, +8, ...
    for (; s + 28 < s1; s += 32) {
        v4 v0 = __builtin_nontemporal_load(base + (size_t)(s +  0) * LD4);
        v4 v1 = __builtin_nontemporal_load(base + (size_t)(s +  4) * LD4);
        v4 v2 = __builtin_nontemporal_load(base + (size_t)(s +  8) * LD4);
        v4 v3 = __builtin_nontemporal_load(base + (size_t)(s + 12) * LD4);
        v4 v4_ = __builtin_nontemporal_load(base + (size_t)(s + 16) * LD4);
        v4 v5 = __builtin_nontemporal_load(base + (size_t)(s + 20) * LD4);
        v4 v6 = __builtin_nontemporal_load(base + (size_t)(s + 24) * LD4);
        v4 v7 = __builtin_nontemporal_load(base + (size_t)(s + 28) * LD4);
        a0 += v0; a1 += v1; a2 += v2; a3 += v3;
        a4 += v4_; a5 += v5; a6 += v6; a7 += v7;
    }
    for (; s < s1; s += 4) {
        a0 += __builtin_nontemporal_load(base + (size_t)s * LD4);
    }
    a0 += a1; a2 += a3; a4 += a5; a6 += a7;
    a0 += a2; a4 += a6; a0 += a4;

    __shared__ v4 red[TPB];
    red[t] = a0;
    __syncthreads();
    if (rg == 0) {
        a0 += red[t + 32];
        a0 += red[t + 64];
        a0 += red[t + 96];
        v4* wsp = reinterpret_cast<v4*>(ws) + ((size_t)b * NS + split) * LD4 + col;
        *wsp = a0;
    }
}

// grid (B, DQ), 128 thr. Thread owns f4-col q*32+lane for split set {rg, rg+4}.
__global__ void __launch_bounds__(TPB)
pool_final(const float* __restrict__ ws, const int* __restrict__ lengths,
           float* __restrict__ out) {
    const int b    = blockIdx.x;
    const int q    = blockIdx.y;
    const int t    = threadIdx.x;
    const int lane = t & 31;
    const int rg   = t >> 5;
    const int col  = q * 32 + lane;

    const int len   = lengths[b];
    const int chunk = (len + NS - 1) / NS;
    const int nact  = (len + chunk - 1) / chunk;   // splits actually written

    const v4* __restrict__ wsp =
        reinterpret_cast<const v4*>(ws) + (size_t)b * NS * LD4 + col;

    v4 a = {0.f,0.f,0.f,0.f};
    for (int p = rg; p < nact; p += 4) {
        a += wsp[(size_t)p * LD4];
    }

    __shared__ v4 red[TPB];
    red[t] = a;
    __syncthreads();
    if (rg == 0) {
        a += red[t + 32];
        a += red[t + 64];
        a += red[t + 96];
        const float inv = 1.0f / (float)len;
        v4 r = a * inv;
        reinterpret_cast<v4*>(out + (size_t)b * DDIM)[col] = r;
    }
}

// Generic fallback: one block per b, full S loop, no ws.
__global__ void __launch_bounds__(TPB)
pool_direct(const float* __restrict__ feat, const int* __restrict__ lengths,
            float* __restrict__ out, int S) {
    const int b   = blockIdx.x;
    const int tid = threadIdx.x;
    const int len = lengths[b];
    v4 a0 = {0.f,0.f,0.f,0.f};
    v4 a1 = {0.f,0.f,0.f,0.f};
    v4 a2 = {0.f,0.f,0.f,0.f};
    v4 a3 = {0.f,0.f,0.f,0.f};
    const v4* __restrict__ base =
        reinterpret_cast<const v4*>(feat + (size_t)b * S * DDIM) + tid;
    int s = 0;
    for (; s + 3 < len; s += 4) {
        v4 v0 = base[(size_t)(s + 0) * LD4];
        v4 v1 = base[(size_t)(s + 1) * LD4];
        v4 v2 = base[(size_t)(s + 2) * LD4];
        v4 v3 = base[(size_t)(s + 3) * LD4];
        a0 += v0; a1 += v1; a2 += v2; a3 += v3;
    }
    for (; s < len; ++s) a0 += base[(size_t)s * LD4];
    a0 += a1; a2 += a3; a0 += a2;
    const float inv = 1.0f / (float)len;
    v4 r = a0 * inv;
    reinterpret_cast<v4*>(out + (size_t)b * DDIM)[tid] = r;
}

extern "C" void kernel_launch(void* const* d_in, const int* in_sizes, int n_in,
                              void* d_out, int out_size, void* d_ws, size_t ws_size,
                              hipStream_t stream) {
    const float* feat    = (const float*)d_in[0];
    const int*   lengths = (const int*)d_in[1];
    float*       out     = (float*)d_out;

    const int B = in_sizes[1];                       // 64
    const int S = in_sizes[0] / (B * DDIM);          // 2048

    const size_t need = (size_t)B * NS * DDIM * sizeof(float);

    if (ws_size >= need && out_size == B * DDIM) {
        float* ws = (float*)d_ws;
        dim3 grid1(B, DQ, NS);
        dim3 grid2(B, DQ);
        pool_partial<<<grid1, TPB, 0, stream>>>(feat, lengths, ws, S);
        pool_final<<<grid2, TPB, 0, stream>>>(ws, lengths, out);
    } else {
        pool_direct<<<B, TPB, 0, stream>>>(feat, lengths, out, S);
    }
}

// Round 11
// 29.636 us; speedup vs baseline: 2.4349x; 1.2595x over previous
//
#include <hip/hip_runtime.h>

// MeanPoolingWithoutPadding: features [B,S,D] f32, lengths [B] i32,
// out [B,D] f32 = sum_{s<len[b]} f[b,s,:] / len[b].  B=64, S=2048, D=512.
//
// R11 = exact revert to R8 (measured best, 29.4 us).
// Eliminated by measurement: atomics into out (R7 42.9), device fences
// (R3 399), dynamic work queue (R9 72.2), nontemporal loads (R10 37.3 --
// they defeat the L3 residency that absorbs ~half the read stream),
// static CU scramble (R6 flat), wide/D-split final variants (R4/R5 flat),
// ws-volume reduction beyond 1 MB (neutral). Plateau ~29.5 us =
// ~5.2 TB/s valid-read rate (82% of D2D ceiling) + ~3 us combine
// structure. Two-phase, deterministic, no atomics:
//   pool_partial: grid (B, DQ=4, NS=8) = 2048 blocks x 128 thr. Block
//     (b,q,split) sums rows [split*chunk,...) of f4-cols [q*32,q*32+32),
//     chunk = ceil(len/8); LDS-combine 4 row groups; one 512 B ws slice.
//   pool_final: grid (B,4) x 128 thr; <=2 partials/thread, LDS combine,
//     scale by 1/len, store.

#define DDIM 512
#define LD4  (DDIM / 4)   // 128 float4 per row
#define NS   8
#define DQ   4
#define TPB  128

__device__ __forceinline__ void acc4(float4& a, const float4& v) {
    a.x += v.x; a.y += v.y; a.z += v.z; a.w += v.w;
}

__global__ void __launch_bounds__(TPB)
pool_partial(const float* __restrict__ feat, const int* __restrict__ lengths,
             float* __restrict__ ws, int S) {
    const int b     = blockIdx.x;
    const int q     = blockIdx.y;        // D-slice
    const int split = blockIdx.z;        // S-slice
    const int t     = threadIdx.x;
    const int lane  = t & 31;            // col lane: 32 f4 = 512 B
    const int rg    = t >> 5;            // row group 0..3

    const int len   = lengths[b];
    const int chunk = (len + NS - 1) / NS;
    const int s0 = split * chunk;
    if (s0 >= len) return;               // inactive: final never reads it
    const int s1 = min(s0 + chunk, len);

    const int col = q * 32 + lane;       // f4 column index
    const float4* __restrict__ base =
        reinterpret_cast<const float4*>(feat + (size_t)b * S * DDIM) + col;

    float4 a0 = {0.f, 0.f, 0.f, 0.f};
    float4 a1 = {0.f, 0.f, 0.f, 0.f};
    float4 a2 = {0.f, 0.f, 0.f, 0.f};
    float4 a3 = {0.f, 0.f, 0.f, 0.f};

    int s = s0 + rg;
    for (; s + 12 < s1; s += 16) {
        float4 v0 = base[(size_t)(s +  0) * LD4];
        float4 v1 = base[(size_t)(s +  4) * LD4];
        float4 v2 = base[(size_t)(s +  8) * LD4];
        float4 v3 = base[(size_t)(s + 12) * LD4];
        acc4(a0, v0); acc4(a1, v1); acc4(a2, v2); acc4(a3, v3);
    }
    for (; s < s1; s += 4) {
        float4 v = base[(size_t)s * LD4];
        acc4(a0, v);
    }
    acc4(a0, a1); acc4(a2, a3); acc4(a0, a2);

    __shared__ float4 red[TPB];
    red[t] = a0;
    __syncthreads();
    if (rg == 0) {
        acc4(a0, red[t + 32]);
        acc4(a0, red[t + 64]);
        acc4(a0, red[t + 96]);
        float4* wsp = reinterpret_cast<float4*>(ws) + ((size_t)b * NS + split) * LD4 + col;
        *wsp = a0;
    }
}

// grid (B, DQ), 128 thr. Thread owns f4-col q*32+lane for split set {rg, rg+4}.
__global__ void __launch_bounds__(TPB)
pool_final(const float* __restrict__ ws, const int* __restrict__ lengths,
           float* __restrict__ out) {
    const int b    = blockIdx.x;
    const int q    = blockIdx.y;
    const int t    = threadIdx.x;
    const int lane = t & 31;
    const int rg   = t >> 5;
    const int col  = q * 32 + lane;

    const int len   = lengths[b];
    const int chunk = (len + NS - 1) / NS;
    const int nact  = (len + chunk - 1) / chunk;   // splits actually written

    const float4* __restrict__ wsp =
        reinterpret_cast<const float4*>(ws) + (size_t)b * NS * LD4 + col;

    float4 a = {0.f, 0.f, 0.f, 0.f};
    for (int p = rg; p < nact; p += 4) {
        acc4(a, wsp[(size_t)p * LD4]);
    }

    __shared__ float4 red[TPB];
    red[t] = a;
    __syncthreads();
    if (rg == 0) {
        acc4(a, red[t + 32]);
        acc4(a, red[t + 64]);
        acc4(a, red[t + 96]);
        const float inv = 1.0f / (float)len;
        float4 r = {a.x * inv, a.y * inv, a.z * inv, a.w * inv};
        reinterpret_cast<float4*>(out + (size_t)b * DDIM)[col] = r;
    }
}

// Generic fallback: one block per b, full S loop, no ws.
__global__ void __launch_bounds__(TPB)
pool_direct(const float* __restrict__ feat, const int* __restrict__ lengths,
            float* __restrict__ out, int S) {
    const int b   = blockIdx.x;
    const int tid = threadIdx.x;
    const int len = lengths[b];
    float4 a0 = {0.f, 0.f, 0.f, 0.f};
    float4 a1 = {0.f, 0.f, 0.f, 0.f};
    float4 a2 = {0.f, 0.f, 0.f, 0.f};
    float4 a3 = {0.f, 0.f, 0.f, 0.f};
    const float4* __restrict__ base =
        reinterpret_cast<const float4*>(feat + (size_t)b * S * DDIM) + tid;
    int s = 0;
    for (; s + 3 < len; s += 4) {
        float4 v0 = base[(size_t)(s + 0) * LD4];
        float4 v1 = base[(size_t)(s + 1) * LD4];
        float4 v2 = base[(size_t)(s + 2) * LD4];
        float4 v3 = base[(size_t)(s + 3) * LD4];
        acc4(a0, v0); acc4(a1, v1); acc4(a2, v2); acc4(a3, v3);
    }
    for (; s < len; ++s) { float4 v = base[(size_t)s * LD4]; acc4(a0, v); }
    acc4(a0, a1); acc4(a2, a3); acc4(a0, a2);
    const float inv = 1.0f / (float)len;
    float4 r = {a0.x * inv, a0.y * inv, a0.z * inv, a0.w * inv};
    reinterpret_cast<float4*>(out + (size_t)b * DDIM)[tid] = r;
}

extern "C" void kernel_launch(void* const* d_in, const int* in_sizes, int n_in,
                              void* d_out, int out_size, void* d_ws, size_t ws_size,
                              hipStream_t stream) {
    const float* feat    = (const float*)d_in[0];
    const int*   lengths = (const int*)d_in[1];
    float*       out     = (float*)d_out;

    const int B = in_sizes[1];                       // 64
    const int S = in_sizes[0] / (B * DDIM);          // 2048

    const size_t need = (size_t)B * NS * DDIM * sizeof(float);

    if (ws_size >= need && out_size == B * DDIM) {
        float* ws = (float*)d_ws;
        dim3 grid1(B, DQ, NS);
        dim3 grid2(B, DQ);
        pool_partial<<<grid1, TPB, 0, stream>>>(feat, lengths, ws, S);
        pool_final<<<grid2, TPB, 0, stream>>>(ws, lengths, out);
    } else {
        pool_direct<<<B, TPB, 0, stream>>>(feat, lengths, out, S);
    }
}